// Round 1
// baseline (713.926 us; speedup 1.0000x reference)
//
#include <hip/hip_runtime.h>
#include <hip/hip_bf16.h>
#include <math.h>

#define B 4096
#define D 1024
#define BM 128
#define BN 128
#define BK 32

typedef float f32x4 __attribute__((ext_vector_type(4)));
typedef short s16x8 __attribute__((ext_vector_type(8)));

__device__ inline void gload_lds16(const void* g, void* l) {
    __builtin_amdgcn_global_load_lds(
        (const __attribute__((address_space(1))) void*)g,
        (__attribute__((address_space(3))) void*)l, 16, 0, 0);
}

// K0: fp32 -> bf16 convert
__global__ __launch_bounds__(256) void convert_kernel(const float* __restrict__ E,
                                                      unsigned short* __restrict__ Ebf) {
    int idx = blockIdx.x * blockDim.x + threadIdx.x;
    const float4* src = (const float4*)E;
    int n4 = B * D / 4;
    for (int i = idx; i < n4; i += gridDim.x * blockDim.x) {
        float4 v = src[i];
        __hip_bfloat16 b0 = __float2bfloat16(v.x);
        __hip_bfloat16 b1 = __float2bfloat16(v.y);
        __hip_bfloat16 b2 = __float2bfloat16(v.z);
        __hip_bfloat16 b3 = __float2bfloat16(v.w);
        ushort4 o;
        o.x = *reinterpret_cast<unsigned short*>(&b0);
        o.y = *reinterpret_cast<unsigned short*>(&b1);
        o.z = *reinterpret_cast<unsigned short*>(&b2);
        o.w = *reinterpret_cast<unsigned short*>(&b3);
        *reinterpret_cast<ushort4*>(&Ebf[i * 4]) = o;
    }
}

// K1: s[d] = sum over rows j with label 0 of E[j][d]
__global__ __launch_bounds__(256) void colsum_kernel(const float* __restrict__ E,
                                                     const int* __restrict__ labels,
                                                     float* __restrict__ s) {
    int d = blockIdx.x * blockDim.x + threadIdx.x;  // 0..D-1 (grid 4 x 256)
    float acc = 0.f;
    for (int j = 0; j < B; ++j) {
        if (labels[j] == 0) acc += E[(size_t)j * D + d];
    }
    s[d] = acc;
}

// K2: per-row selfdot = <e_i,e_i>, rawpos = <e_i, s>
__global__ __launch_bounds__(256) void rowstats_kernel(const float* __restrict__ E,
                                                       const float* __restrict__ s,
                                                       float* __restrict__ selfdot,
                                                       float* __restrict__ rawpos) {
    int wave = threadIdx.x >> 6;
    int lane = threadIdx.x & 63;
    int row = blockIdx.x * 4 + wave;
    const float4* er = (const float4*)(E + (size_t)row * D);
    const float4* s4 = (const float4*)s;
    float sd = 0.f, pp = 0.f;
    for (int it = 0; it < D / 4 / 64; ++it) {
        int k4 = it * 64 + lane;
        float4 v = er[k4];
        float4 w = s4[k4];
        sd += v.x * v.x + v.y * v.y + v.z * v.z + v.w * v.w;
        pp += v.x * w.x + v.y * w.y + v.z * w.z + v.w * w.w;
    }
    for (int m = 32; m; m >>= 1) {
        sd += __shfl_xor(sd, m, 64);
        pp += __shfl_xor(pp, m, 64);
    }
    if (lane == 0) {
        selfdot[row] = sd;
        rawpos[row] = pp;
    }
}

// K3: main flash kernel — denomsum[i] += sum_j exp(<e_i,e_j>_bf16), diagonal masked
__global__ __launch_bounds__(256) void simexp_kernel(const unsigned short* __restrict__ Ebf,
                                                     float* __restrict__ denomsum) {
    __shared__ short As[BM * BK];
    __shared__ short Bs[BN * BK];
    const int tid = threadIdx.x;
    const int lane = tid & 63;
    const int wave = tid >> 6;
    const int wr = wave >> 1, wc = wave & 1;
    const int rowBase = blockIdx.y * BM;
    const int colBase = blockIdx.x * BN;

    f32x4 acc[4][4];
#pragma unroll
    for (int i = 0; i < 4; i++)
#pragma unroll
        for (int j = 0; j < 4; j++) acc[i][j] = (f32x4)(0.f);

    const short* gbase = (const short*)Ebf;

    for (int kk = 0; kk < D / BK; ++kk) {
#pragma unroll
        for (int q = 0; q < 2; ++q) {
            int c = wave * 128 + q * 64 + lane;  // 16B chunk index in tile
            int r = c >> 2;                      // tile row
            int c8 = (c & 3) * 8;                // element offset within row
            const short* ga = gbase + (size_t)(rowBase + r) * D + kk * BK + c8;
            const short* gb = gbase + (size_t)(colBase + r) * D + kk * BK + c8;
            gload_lds16(ga, &As[c * 8]);
            gload_lds16(gb, &Bs[c * 8]);
        }
        __syncthreads();
        s16x8 afrag[4], bfrag[4];
        int ko = (lane >> 4) * 8;
#pragma unroll
        for (int mi = 0; mi < 4; ++mi)
            afrag[mi] = *(const s16x8*)&As[(wr * 64 + mi * 16 + (lane & 15)) * BK + ko];
#pragma unroll
        for (int ni = 0; ni < 4; ++ni)
            bfrag[ni] = *(const s16x8*)&Bs[(wc * 64 + ni * 16 + (lane & 15)) * BK + ko];
#pragma unroll
        for (int mi = 0; mi < 4; ++mi)
#pragma unroll
            for (int ni = 0; ni < 4; ++ni)
                acc[mi][ni] = __builtin_amdgcn_mfma_f32_16x16x32_bf16(
                    afrag[mi], bfrag[ni], acc[mi][ni], 0, 0, 0);
        __syncthreads();
    }

    // epilogue: exp, mask diagonal, per-row partial sums, reduce over lane&15, atomicAdd
    float part[4][4];
#pragma unroll
    for (int mi = 0; mi < 4; mi++)
#pragma unroll
        for (int r = 0; r < 4; r++) part[mi][r] = 0.f;
    int rquad = (lane >> 4) * 4;
    int lcol = lane & 15;
#pragma unroll
    for (int mi = 0; mi < 4; mi++) {
#pragma unroll
        for (int ni = 0; ni < 4; ni++) {
            int gcol = colBase + wc * 64 + ni * 16 + lcol;
#pragma unroll
            for (int r = 0; r < 4; r++) {
                int grow = rowBase + wr * 64 + mi * 16 + rquad + r;
                float e = __expf(acc[mi][ni][r]);
                if (grow == gcol) e = 0.f;
                part[mi][r] += e;
            }
        }
    }
#pragma unroll
    for (int m = 1; m < 16; m <<= 1) {
#pragma unroll
        for (int mi = 0; mi < 4; mi++)
#pragma unroll
            for (int r = 0; r < 4; r++) part[mi][r] += __shfl_xor(part[mi][r], m, 64);
    }
    if (lcol == 0) {
#pragma unroll
        for (int mi = 0; mi < 4; mi++)
#pragma unroll
            for (int r = 0; r < 4; r++) {
                int grow = rowBase + wr * 64 + mi * 16 + rquad + r;
                atomicAdd(&denomsum[grow], part[mi][r]);
            }
    }
}

// K4: finalize scalar loss
__global__ __launch_bounds__(256) void finalize_kernel(const int* __restrict__ labels,
                                                       const float* __restrict__ denomsum,
                                                       const float* __restrict__ selfdot,
                                                       const float* __restrict__ rawpos,
                                                       float* __restrict__ out) {
    __shared__ int nnorm_sh;
    __shared__ float tot_sh;
    int tid = threadIdx.x;
    if (tid == 0) {
        nnorm_sh = 0;
        tot_sh = 0.f;
    }
    __syncthreads();
    int c = 0;
    for (int j = tid; j < B; j += 256) c += (labels[j] == 0) ? 1 : 0;
    atomicAdd(&nnorm_sh, c);
    __syncthreads();
    int n_normal = nnorm_sh;
    float local = 0.f;
    for (int i = tid; i < B; i += 256) {
        if (labels[i] == 0) {
            int cntp = n_normal - 1;
            float rl = 0.f;
            if (cntp > 0) {
                float possum = rawpos[i] - selfdot[i];
                rl = logf(denomsum[i]) - possum / (float)cntp;
            }
            local += rl;
        }
    }
    atomicAdd(&tot_sh, local);
    __syncthreads();
    if (tid == 0) out[0] = (n_normal > 0) ? tot_sh / (float)n_normal : 0.f;
}

extern "C" void kernel_launch(void* const* d_in, const int* in_sizes, int n_in,
                              void* d_out, int out_size, void* d_ws, size_t ws_size,
                              hipStream_t stream) {
    const float* E = (const float*)d_in[0];
    const int* labels = (const int*)d_in[1];
    float* out = (float*)d_out;

    char* ws = (char*)d_ws;
    unsigned short* Ebf = (unsigned short*)ws;                      // 8 MB
    float* s = (float*)(ws + (size_t)B * D * 2);                    // 4 KB
    float* selfdot = (float*)(ws + (size_t)B * D * 2 + 4096);       // 16 KB
    float* rawpos = (float*)(ws + (size_t)B * D * 2 + 4096 + 16384);
    float* denomsum = (float*)(ws + (size_t)B * D * 2 + 4096 + 2 * 16384);

    convert_kernel<<<1024, 256, 0, stream>>>(E, Ebf);
    colsum_kernel<<<D / 256, 256, 0, stream>>>(E, labels, s);
    hipMemsetAsync(denomsum, 0, B * sizeof(float), stream);
    rowstats_kernel<<<B / 4, 256, 0, stream>>>(E, s, selfdot, rawpos);
    dim3 grid(B / BN, B / BM);
    simexp_kernel<<<grid, 256, 0, stream>>>(Ebf, denomsum);
    finalize_kernel<<<1, 256, 0, stream>>>(labels, denomsum, selfdot, rawpos, out);
}

// Round 2
// 109.187 us; speedup vs baseline: 6.5385x; 6.5385x over previous
//
#include <hip/hip_runtime.h>
#include <hip/hip_bf16.h>
#include <math.h>

#define B 4096
#define D 1024
#define BM 128
#define BN 128
#define BK 32

#define CS_BLOCKS 256
#define CS_ROWS (B / CS_BLOCKS)  // 16

typedef float f32x4 __attribute__((ext_vector_type(4)));
typedef short s16x8 __attribute__((ext_vector_type(8)));

__device__ inline void gload_lds16(const void* g, void* l) {
    __builtin_amdgcn_global_load_lds(
        (const __attribute__((address_space(1))) void*)g,
        (__attribute__((address_space(3))) void*)l, 16, 0, 0);
}

// K0: fp32 -> bf16 convert
__global__ __launch_bounds__(256) void convert_kernel(const float* __restrict__ E,
                                                      unsigned short* __restrict__ Ebf) {
    int idx = blockIdx.x * blockDim.x + threadIdx.x;
    const float4* src = (const float4*)E;
    int n4 = B * D / 4;
    for (int i = idx; i < n4; i += gridDim.x * blockDim.x) {
        float4 v = src[i];
        __hip_bfloat16 b0 = __float2bfloat16(v.x);
        __hip_bfloat16 b1 = __float2bfloat16(v.y);
        __hip_bfloat16 b2 = __float2bfloat16(v.z);
        __hip_bfloat16 b3 = __float2bfloat16(v.w);
        ushort4 o;
        o.x = *reinterpret_cast<unsigned short*>(&b0);
        o.y = *reinterpret_cast<unsigned short*>(&b1);
        o.z = *reinterpret_cast<unsigned short*>(&b2);
        o.w = *reinterpret_cast<unsigned short*>(&b3);
        *reinterpret_cast<ushort4*>(&Ebf[i * 4]) = o;
    }
}

// K1a: per-block partial label-masked column sums.
// Block b owns rows [b*16, b*16+16); thread t owns columns [t*4, t*4+4).
__global__ __launch_bounds__(256) void colsum_part_kernel(const float* __restrict__ E,
                                                          const int* __restrict__ labels,
                                                          float* __restrict__ partial) {
    int tid = threadIdx.x;
    int b = blockIdx.x;
    float4 acc = {0.f, 0.f, 0.f, 0.f};
    int r0 = b * CS_ROWS;
#pragma unroll 4
    for (int j = r0; j < r0 + CS_ROWS; ++j) {
        if (labels[j] == 0) {
            float4 v = *(const float4*)(E + (size_t)j * D + tid * 4);
            acc.x += v.x;
            acc.y += v.y;
            acc.z += v.z;
            acc.w += v.w;
        }
    }
    *(float4*)(partial + (size_t)b * D + tid * 4) = acc;
}

// K1b: reduce partials -> s[d]
__global__ __launch_bounds__(256) void colsum_reduce_kernel(const float* __restrict__ partial,
                                                            float* __restrict__ s) {
    int d = blockIdx.x * 256 + threadIdx.x;
    float acc = 0.f;
    for (int p = 0; p < CS_BLOCKS; ++p) acc += partial[(size_t)p * D + d];
    s[d] = acc;
}

// K2: per-row selfdot = <e_i,e_i>, rawpos = <e_i, s>
__global__ __launch_bounds__(256) void rowstats_kernel(const float* __restrict__ E,
                                                       const float* __restrict__ s,
                                                       float* __restrict__ selfdot,
                                                       float* __restrict__ rawpos) {
    int wave = threadIdx.x >> 6;
    int lane = threadIdx.x & 63;
    int row = blockIdx.x * 4 + wave;
    const float4* er = (const float4*)(E + (size_t)row * D);
    const float4* s4 = (const float4*)s;
    float sd = 0.f, pp = 0.f;
    for (int it = 0; it < D / 4 / 64; ++it) {
        int k4 = it * 64 + lane;
        float4 v = er[k4];
        float4 w = s4[k4];
        sd += v.x * v.x + v.y * v.y + v.z * v.z + v.w * v.w;
        pp += v.x * w.x + v.y * w.y + v.z * w.z + v.w * w.w;
    }
    for (int m = 32; m; m >>= 1) {
        sd += __shfl_xor(sd, m, 64);
        pp += __shfl_xor(pp, m, 64);
    }
    if (lane == 0) {
        selfdot[row] = sd;
        rawpos[row] = pp;
    }
}

// K3: main flash kernel — denomsum[i] += sum_j exp(<e_i,e_j>_bf16), diagonal masked
__global__ __launch_bounds__(256) void simexp_kernel(const unsigned short* __restrict__ Ebf,
                                                     float* __restrict__ denomsum) {
    __shared__ short As[BM * BK];
    __shared__ short Bs[BN * BK];
    const int tid = threadIdx.x;
    const int lane = tid & 63;
    const int wave = tid >> 6;
    const int wr = wave >> 1, wc = wave & 1;
    const int rowBase = blockIdx.y * BM;
    const int colBase = blockIdx.x * BN;

    f32x4 acc[4][4];
#pragma unroll
    for (int i = 0; i < 4; i++)
#pragma unroll
        for (int j = 0; j < 4; j++) acc[i][j] = (f32x4)(0.f);

    const short* gbase = (const short*)Ebf;

    for (int kk = 0; kk < D / BK; ++kk) {
#pragma unroll
        for (int q = 0; q < 2; ++q) {
            int c = wave * 128 + q * 64 + lane;  // 16B chunk index in tile
            int r = c >> 2;                      // tile row
            int c8 = (c & 3) * 8;                // element offset within row
            const short* ga = gbase + (size_t)(rowBase + r) * D + kk * BK + c8;
            const short* gb = gbase + (size_t)(colBase + r) * D + kk * BK + c8;
            gload_lds16(ga, &As[c * 8]);
            gload_lds16(gb, &Bs[c * 8]);
        }
        __syncthreads();
        s16x8 afrag[4], bfrag[4];
        int ko = (lane >> 4) * 8;
#pragma unroll
        for (int mi = 0; mi < 4; ++mi)
            afrag[mi] = *(const s16x8*)&As[(wr * 64 + mi * 16 + (lane & 15)) * BK + ko];
#pragma unroll
        for (int ni = 0; ni < 4; ++ni)
            bfrag[ni] = *(const s16x8*)&Bs[(wc * 64 + ni * 16 + (lane & 15)) * BK + ko];
#pragma unroll
        for (int mi = 0; mi < 4; ++mi)
#pragma unroll
            for (int ni = 0; ni < 4; ++ni)
                acc[mi][ni] = __builtin_amdgcn_mfma_f32_16x16x32_bf16(
                    afrag[mi], bfrag[ni], acc[mi][ni], 0, 0, 0);
        __syncthreads();
    }

    // epilogue: exp, mask diagonal, per-row partial sums, reduce over lane&15, atomicAdd
    float part[4][4];
#pragma unroll
    for (int mi = 0; mi < 4; mi++)
#pragma unroll
        for (int r = 0; r < 4; r++) part[mi][r] = 0.f;
    int rquad = (lane >> 4) * 4;
    int lcol = lane & 15;
#pragma unroll
    for (int mi = 0; mi < 4; mi++) {
#pragma unroll
        for (int ni = 0; ni < 4; ni++) {
            int gcol = colBase + wc * 64 + ni * 16 + lcol;
#pragma unroll
            for (int r = 0; r < 4; r++) {
                int grow = rowBase + wr * 64 + mi * 16 + rquad + r;
                float e = __expf(acc[mi][ni][r]);
                if (grow == gcol) e = 0.f;
                part[mi][r] += e;
            }
        }
    }
#pragma unroll
    for (int m = 1; m < 16; m <<= 1) {
#pragma unroll
        for (int mi = 0; mi < 4; mi++)
#pragma unroll
            for (int r = 0; r < 4; r++) part[mi][r] += __shfl_xor(part[mi][r], m, 64);
    }
    if (lcol == 0) {
#pragma unroll
        for (int mi = 0; mi < 4; mi++)
#pragma unroll
            for (int r = 0; r < 4; r++) {
                int grow = rowBase + wr * 64 + mi * 16 + rquad + r;
                atomicAdd(&denomsum[grow], part[mi][r]);
            }
    }
}

// K4: finalize scalar loss
__global__ __launch_bounds__(256) void finalize_kernel(const int* __restrict__ labels,
                                                       const float* __restrict__ denomsum,
                                                       const float* __restrict__ selfdot,
                                                       const float* __restrict__ rawpos,
                                                       float* __restrict__ out) {
    __shared__ int nnorm_sh;
    __shared__ float tot_sh;
    int tid = threadIdx.x;
    if (tid == 0) {
        nnorm_sh = 0;
        tot_sh = 0.f;
    }
    __syncthreads();
    int c = 0;
    for (int j = tid; j < B; j += 256) c += (labels[j] == 0) ? 1 : 0;
    atomicAdd(&nnorm_sh, c);
    __syncthreads();
    int n_normal = nnorm_sh;
    float local = 0.f;
    for (int i = tid; i < B; i += 256) {
        if (labels[i] == 0) {
            int cntp = n_normal - 1;
            float rl = 0.f;
            if (cntp > 0) {
                float possum = rawpos[i] - selfdot[i];
                rl = logf(denomsum[i]) - possum / (float)cntp;
            }
            local += rl;
        }
    }
    atomicAdd(&tot_sh, local);
    __syncthreads();
    if (tid == 0) out[0] = (n_normal > 0) ? tot_sh / (float)n_normal : 0.f;
}

extern "C" void kernel_launch(void* const* d_in, const int* in_sizes, int n_in,
                              void* d_out, int out_size, void* d_ws, size_t ws_size,
                              hipStream_t stream) {
    const float* E = (const float*)d_in[0];
    const int* labels = (const int*)d_in[1];
    float* out = (float*)d_out;

    char* ws = (char*)d_ws;
    size_t off = 0;
    unsigned short* Ebf = (unsigned short*)(ws + off);
    off += (size_t)B * D * 2;  // 8 MB
    float* s = (float*)(ws + off);
    off += D * sizeof(float);  // 4 KB
    float* selfdot = (float*)(ws + off);
    off += B * sizeof(float);  // 16 KB
    float* rawpos = (float*)(ws + off);
    off += B * sizeof(float);  // 16 KB
    float* denomsum = (float*)(ws + off);
    off += B * sizeof(float);  // 16 KB
    float* partial = (float*)(ws + off);
    off += (size_t)CS_BLOCKS * D * sizeof(float);  // 1 MB

    convert_kernel<<<1024, 256, 0, stream>>>(E, Ebf);
    colsum_part_kernel<<<CS_BLOCKS, 256, 0, stream>>>(E, labels, partial);
    colsum_reduce_kernel<<<D / 256, 256, 0, stream>>>(partial, s);
    hipMemsetAsync(denomsum, 0, B * sizeof(float), stream);
    rowstats_kernel<<<B / 4, 256, 0, stream>>>(E, s, selfdot, rawpos);
    dim3 grid(B / BN, B / BM);
    simexp_kernel<<<grid, 256, 0, stream>>>(Ebf, denomsum);
    finalize_kernel<<<1, 256, 0, stream>>>(labels, denomsum, selfdot, rawpos, out);
}

// Round 3
// 74.425 us; speedup vs baseline: 9.5925x; 1.4671x over previous
//
#include <hip/hip_runtime.h>
#include <hip/hip_bf16.h>
#include <math.h>

#define B 4096
#define D 1024
#define BM 128
#define BN 128
#define BK 32
#define NBLK (B / BM)  // 32 row/col blocks
#define NTRI (NBLK * (NBLK + 1) / 2)  // 528 upper-tri blocks

#define CS_BLOCKS 256
#define CS_ROWS (B / CS_BLOCKS)  // 16

typedef float f32x4 __attribute__((ext_vector_type(4)));
typedef short s16x8 __attribute__((ext_vector_type(8)));

__device__ inline void gload_lds16(const void* g, void* l) {
    __builtin_amdgcn_global_load_lds(
        (const __attribute__((address_space(1))) void*)g,
        (__attribute__((address_space(3))) void*)l, 16, 0, 0);
}

// K0: fused fp32->bf16 convert + label-masked partial column sums.
// Block b owns rows [b*16, b*16+16); thread t owns columns [t*4, t*4+4).
__global__ __launch_bounds__(256) void prep_kernel(const float* __restrict__ E,
                                                   const int* __restrict__ labels,
                                                   unsigned short* __restrict__ Ebf,
                                                   float* __restrict__ partial) {
    int tid = threadIdx.x;
    int b = blockIdx.x;
    float4 acc = {0.f, 0.f, 0.f, 0.f};
    int r0 = b * CS_ROWS;
#pragma unroll 4
    for (int j = r0; j < r0 + CS_ROWS; ++j) {
        float4 v = *(const float4*)(E + (size_t)j * D + tid * 4);
        __hip_bfloat16 b0 = __float2bfloat16(v.x);
        __hip_bfloat16 b1 = __float2bfloat16(v.y);
        __hip_bfloat16 b2 = __float2bfloat16(v.z);
        __hip_bfloat16 b3 = __float2bfloat16(v.w);
        ushort4 o;
        o.x = *reinterpret_cast<unsigned short*>(&b0);
        o.y = *reinterpret_cast<unsigned short*>(&b1);
        o.z = *reinterpret_cast<unsigned short*>(&b2);
        o.w = *reinterpret_cast<unsigned short*>(&b3);
        *reinterpret_cast<ushort4*>(&Ebf[(size_t)j * D + tid * 4]) = o;
        if (labels[j] == 0) {
            acc.x += v.x;
            acc.y += v.y;
            acc.z += v.z;
            acc.w += v.w;
        }
    }
    *(float4*)(partial + (size_t)b * D + tid * 4) = acc;
}

// K1: reduce partials -> s[d]; also zero denomsum.
__global__ __launch_bounds__(256) void colsum_reduce_kernel(const float* __restrict__ partial,
                                                            float* __restrict__ s,
                                                            float* __restrict__ denomsum) {
    int d = blockIdx.x * 256 + threadIdx.x;
    float acc = 0.f;
    for (int p = 0; p < CS_BLOCKS; ++p) acc += partial[(size_t)p * D + d];
    s[d] = acc;
    for (int i = d; i < B; i += D) denomsum[i] = 0.f;
}

// K2: per-row selfdot = <e_i,e_i>, rawpos = <e_i, s>
__global__ __launch_bounds__(256) void rowstats_kernel(const float* __restrict__ E,
                                                       const float* __restrict__ s,
                                                       float* __restrict__ selfdot,
                                                       float* __restrict__ rawpos) {
    int wave = threadIdx.x >> 6;
    int lane = threadIdx.x & 63;
    int row = blockIdx.x * 4 + wave;
    const float4* er = (const float4*)(E + (size_t)row * D);
    const float4* s4 = (const float4*)s;
    float sd = 0.f, pp = 0.f;
    for (int it = 0; it < D / 4 / 64; ++it) {
        int k4 = it * 64 + lane;
        float4 v = er[k4];
        float4 w = s4[k4];
        sd += v.x * v.x + v.y * v.y + v.z * v.z + v.w * v.w;
        pp += v.x * w.x + v.y * w.y + v.z * w.z + v.w * w.w;
    }
    for (int m = 32; m; m >>= 1) {
        sd += __shfl_xor(sd, m, 64);
        pp += __shfl_xor(pp, m, 64);
    }
    if (lane == 0) {
        selfdot[row] = sd;
        rawpos[row] = pp;
    }
}

// K3: symmetric flash kernel over upper-triangular blocks.
// Off-diagonal block (bi<bj): row-sums -> denomsum[rows], col-sums -> denomsum[cols].
// Diagonal block (bi==bj): mask diagonal, row-sums only.
__global__ __launch_bounds__(256) void simexp_sym_kernel(const unsigned short* __restrict__ Ebf,
                                                         float* __restrict__ denomsum) {
    __shared__ short As[BM * BK];
    __shared__ short Bs[BN * BK];
    const int tid = threadIdx.x;
    const int lane = tid & 63;
    const int wave = tid >> 6;
    const int wr = wave >> 1, wc = wave & 1;

    // map linear block id -> upper-triangular (bi, bj), bj >= bi
    int t = blockIdx.x;
    int bi = 0;
    int rowcnt = NBLK;
    while (t >= rowcnt) {
        t -= rowcnt;
        bi++;
        rowcnt--;
    }
    int bj = bi + t;
    const bool isDiag = (bi == bj);
    const int rowBase = bi * BM;
    const int colBase = bj * BN;

    f32x4 acc[4][4];
#pragma unroll
    for (int i = 0; i < 4; i++)
#pragma unroll
        for (int j = 0; j < 4; j++) acc[i][j] = (f32x4)(0.f);

    const short* gbase = (const short*)Ebf;

    for (int kk = 0; kk < D / BK; ++kk) {
#pragma unroll
        for (int q = 0; q < 2; ++q) {
            int c = wave * 128 + q * 64 + lane;  // 16B chunk index in tile
            int r = c >> 2;                      // tile row
            int c8 = (c & 3) * 8;                // element offset within row
            const short* ga = gbase + (size_t)(rowBase + r) * D + kk * BK + c8;
            const short* gb = gbase + (size_t)(colBase + r) * D + kk * BK + c8;
            gload_lds16(ga, &As[c * 8]);
            gload_lds16(gb, &Bs[c * 8]);
        }
        __syncthreads();
        s16x8 afrag[4], bfrag[4];
        int ko = (lane >> 4) * 8;
#pragma unroll
        for (int mi = 0; mi < 4; ++mi)
            afrag[mi] = *(const s16x8*)&As[(wr * 64 + mi * 16 + (lane & 15)) * BK + ko];
#pragma unroll
        for (int ni = 0; ni < 4; ++ni)
            bfrag[ni] = *(const s16x8*)&Bs[(wc * 64 + ni * 16 + (lane & 15)) * BK + ko];
#pragma unroll
        for (int mi = 0; mi < 4; ++mi)
#pragma unroll
            for (int ni = 0; ni < 4; ++ni)
                acc[mi][ni] = __builtin_amdgcn_mfma_f32_16x16x32_bf16(
                    afrag[mi], bfrag[ni], acc[mi][ni], 0, 0, 0);
        __syncthreads();
    }

    // epilogue: exp, mask diag, row partial sums + (off-diag) col partial sums
    float part[4][4];   // [mi][r] row partials
    float colpart[4];   // [ni] col partials (this lane's 16 rows)
#pragma unroll
    for (int mi = 0; mi < 4; mi++)
#pragma unroll
        for (int r = 0; r < 4; r++) part[mi][r] = 0.f;
#pragma unroll
    for (int ni = 0; ni < 4; ni++) colpart[ni] = 0.f;

    int rquad = (lane >> 4) * 4;
    int lcol = lane & 15;
#pragma unroll
    for (int mi = 0; mi < 4; mi++) {
#pragma unroll
        for (int ni = 0; ni < 4; ni++) {
            int gcol = colBase + wc * 64 + ni * 16 + lcol;
#pragma unroll
            for (int r = 0; r < 4; r++) {
                int grow = rowBase + wr * 64 + mi * 16 + rquad + r;
                float e = __expf(acc[mi][ni][r]);
                if (grow == gcol) e = 0.f;  // only possible when isDiag
                part[mi][r] += e;
                colpart[ni] += e;
            }
        }
    }

    // row reduce over lcol (xor 1,2,4,8), atomicAdd per row
#pragma unroll
    for (int m = 1; m < 16; m <<= 1) {
#pragma unroll
        for (int mi = 0; mi < 4; mi++)
#pragma unroll
            for (int r = 0; r < 4; r++) part[mi][r] += __shfl_xor(part[mi][r], m, 64);
    }
    if (lcol == 0) {
#pragma unroll
        for (int mi = 0; mi < 4; mi++)
#pragma unroll
            for (int r = 0; r < 4; r++) {
                int grow = rowBase + wr * 64 + mi * 16 + rquad + r;
                atomicAdd(&denomsum[grow], part[mi][r]);
            }
    }

    // col reduce over lane-groups (xor 16,32), atomicAdd per col — off-diag only
    if (!isDiag) {
#pragma unroll
        for (int ni = 0; ni < 4; ni++) {
            colpart[ni] += __shfl_xor(colpart[ni], 16, 64);
            colpart[ni] += __shfl_xor(colpart[ni], 32, 64);
        }
        if (lane < 16) {
#pragma unroll
            for (int ni = 0; ni < 4; ni++) {
                int gcol = colBase + wc * 64 + ni * 16 + lane;
                atomicAdd(&denomsum[gcol], colpart[ni]);
            }
        }
    }
}

// K4: finalize scalar loss
__global__ __launch_bounds__(256) void finalize_kernel(const int* __restrict__ labels,
                                                       const float* __restrict__ denomsum,
                                                       const float* __restrict__ selfdot,
                                                       const float* __restrict__ rawpos,
                                                       float* __restrict__ out) {
    __shared__ int nnorm_sh;
    __shared__ float tot_sh;
    int tid = threadIdx.x;
    if (tid == 0) {
        nnorm_sh = 0;
        tot_sh = 0.f;
    }
    __syncthreads();
    int c = 0;
    for (int j = tid; j < B; j += 256) c += (labels[j] == 0) ? 1 : 0;
    atomicAdd(&nnorm_sh, c);
    __syncthreads();
    int n_normal = nnorm_sh;
    float local = 0.f;
    for (int i = tid; i < B; i += 256) {
        if (labels[i] == 0) {
            int cntp = n_normal - 1;
            float rl = 0.f;
            if (cntp > 0) {
                float possum = rawpos[i] - selfdot[i];
                rl = logf(denomsum[i]) - possum / (float)cntp;
            }
            local += rl;
        }
    }
    atomicAdd(&tot_sh, local);
    __syncthreads();
    if (tid == 0) out[0] = (n_normal > 0) ? tot_sh / (float)n_normal : 0.f;
}

extern "C" void kernel_launch(void* const* d_in, const int* in_sizes, int n_in,
                              void* d_out, int out_size, void* d_ws, size_t ws_size,
                              hipStream_t stream) {
    const float* E = (const float*)d_in[0];
    const int* labels = (const int*)d_in[1];
    float* out = (float*)d_out;

    char* ws = (char*)d_ws;
    size_t off = 0;
    unsigned short* Ebf = (unsigned short*)(ws + off);
    off += (size_t)B * D * 2;  // 8 MB
    float* s = (float*)(ws + off);
    off += D * sizeof(float);  // 4 KB
    float* selfdot = (float*)(ws + off);
    off += B * sizeof(float);  // 16 KB
    float* rawpos = (float*)(ws + off);
    off += B * sizeof(float);  // 16 KB
    float* denomsum = (float*)(ws + off);
    off += B * sizeof(float);  // 16 KB
    float* partial = (float*)(ws + off);
    off += (size_t)CS_BLOCKS * D * sizeof(float);  // 1 MB

    prep_kernel<<<CS_BLOCKS, 256, 0, stream>>>(E, labels, Ebf, partial);
    colsum_reduce_kernel<<<D / 256, 256, 0, stream>>>(partial, s, denomsum);
    rowstats_kernel<<<B / 4, 256, 0, stream>>>(E, s, selfdot, rawpos);
    simexp_sym_kernel<<<NTRI, 256, 0, stream>>>(Ebf, denomsum);
    finalize_kernel<<<1, 256, 0, stream>>>(labels, denomsum, selfdot, rawpos, out);
}